// Round 20
// baseline (200.505 us; speedup 1.0000x reference)
//
#include <hip/hip_runtime.h>

#define MDIM 8192
#define NDIM 4096
#define KDIM 4096
#define QS 21.1666666f      // 127/6
#define INVQS (6.0f / 127.0f)

typedef __attribute__((ext_vector_type(8))) short short8;
typedef __attribute__((ext_vector_type(4))) float f32x4;
typedef __attribute__((ext_vector_type(4))) int int4v;
typedef __attribute__((ext_vector_type(16))) int i32x16;
typedef __attribute__((ext_vector_type(16))) char char16;
typedef unsigned short u16;
typedef unsigned int u32;

__device__ __forceinline__ u16 f2bf(float f) {
  return __builtin_bit_cast(u16, static_cast<__bf16>(f));
}

// ---------------- prepass: x f32 -> i8 frag-linear; W -> (q-zp1) i8 frag-linear ----
// (r16-verified; numerics frozen)
__global__ __launch_bounds__(256) void prep_kernel(const float* __restrict__ x,
                                                   char* __restrict__ xi,
                                                   const int* __restrict__ qw,
                                                   const int* __restrict__ qz,
                                                   char* __restrict__ wi) {
  const int b = blockIdx.x;
  if (b < 8192) {
    const u32 u = b * 256 + threadIdx.x;      // 0..2097151
    const int lane = u & 63;
    const int kblk = (u >> 6) & 127;
    const int mblk = u >> 13;                 // 0..255
    const int m = mblk * 32 + (lane & 31);
    const int k0 = kblk * 32 + (lane >> 5) * 16;
    const float* p = x + (size_t)m * KDIM + k0;
    char16 v;
#pragma unroll
    for (int c4 = 0; c4 < 4; ++c4) {
      const f32x4 a = *(const f32x4*)(p + c4 * 4);
#pragma unroll
      for (int j = 0; j < 4; ++j) {
        const int q = __float2int_rn(fminf(fmaxf(a[j] * QS, -127.f), 127.f));
        v[c4 * 4 + j] = (char)q;
      }
    }
    *(char16*)(xi + (size_t)u * 16) = v;
  } else {
    const u32 u = (b - 8192) * 256 + threadIdx.x;  // 0..1048575
    const int lane = u & 63;
    const int kblk = (u >> 6) & 127;
    const int nblk = u >> 13;                 // 0..127
    const int n = nblk * 32 + (lane & 31);
    const int kp0 = kblk * 4 + (lane >> 5) * 2;
    const int zw = qz[n >> 3];
    const int zp1 = ((zw >> ((n & 7) * 4)) & 0xF) + 1;
    char16 v;
#pragma unroll
    for (int h = 0; h < 2; ++h) {
      const int w = qw[(size_t)(kp0 + h) * NDIM + n];
#pragma unroll
      for (int j = 0; j < 8; ++j)
        v[h * 8 + j] = (char)(((w >> (4 * j)) & 0xF) - zp1);
    }
    *(char16*)(wi + (size_t)u * 16) = v;
  }
}

// ---------------- main GEMM: i8 32x32x32, 128x128 tile, 4 blocks/CU (16 waves) ------
// Slim registers: acc 64 AGPR + ~60 VGPR -> 4 waves/SIMD (the 2-wave/SIMD ~50%
// MFMA-rate cap was the cross-round limiter).  A via glds->LDS 2-deep; B via
// k-chunk time-shared regs (bX=kw01, bY=kw23).  1 barrier/K-tile; STGA after
// BAR (WAR-safe); prev STGA forced by bY's auto-vmcnt one K-tile before use.
#define BAR()    __builtin_amdgcn_s_barrier()
#define FENCE()  __builtin_amdgcn_sched_barrier(0)
#define VM4()    asm volatile("s_waitcnt vmcnt(4)" ::: "memory")
#define PRIO1()  __builtin_amdgcn_s_setprio(1)
#define PRIO0()  __builtin_amdgcn_s_setprio(0)

// stage A K-tile T (128 rows x 128 k = 16KB) into buffer BUF: 4 glds rounds
#define STGA(BUF, T) do {                                                     \
    _Pragma("unroll")                                                         \
    for (int r_ = 0; r_ < 4; ++r_) {                                          \
      __builtin_amdgcn_global_load_lds(                                       \
        (const __attribute__((address_space(1))) void*)                       \
          (pA4[r_] + (size_t)(T) * 4096),                                     \
        (__attribute__((address_space(3))) void*)                             \
          (AsB + (BUF) * 16384 + r_ * 4096 + tid * 16), 16, 0, 0);            \
    }                                                                         \
  } while (0)

// load half-chunk of B: 4 frags (fn 0..1 x kw {KW0,KW0+1}) of K-tile TN
#define LDBH(SET, TN, KW0) do {                                               \
    _Pragma("unroll")                                                         \
    for (int fn_ = 0; fn_ < 2; ++fn_)                                         \
      _Pragma("unroll")                                                       \
      for (int j_ = 0; j_ < 2; ++j_)                                          \
        SET[fn_ * 2 + j_] = *(const int4v*)(pB0 + (size_t)fn_ * 131072 +      \
            (size_t)(TN) * 4096 + ((KW0) + j_) * 1024);                       \
  } while (0)

// half-K-tile compute: kw {KW0,KW0+1}: 2 A-reads + 4 MFMA each
#define MFH(BUF, SET, KW0) do {                                               \
    _Pragma("unroll")                                                         \
    for (int j_ = 0; j_ < 2; ++j_) {                                          \
      const char* a_ = AsB + (BUF) * 16384 + abase + ((KW0) + j_) * 1024 + l16;\
      int4v aq0 = *(const int4v*)(a_);                                        \
      int4v aq1 = *(const int4v*)(a_ + 4096);                                 \
      acc[0][0] = __builtin_amdgcn_mfma_i32_32x32x32_i8(aq0, SET[0 * 2 + j_], acc[0][0], 0, 0, 0); \
      acc[1][0] = __builtin_amdgcn_mfma_i32_32x32x32_i8(aq1, SET[0 * 2 + j_], acc[1][0], 0, 0, 0); \
      acc[0][1] = __builtin_amdgcn_mfma_i32_32x32x32_i8(aq0, SET[1 * 2 + j_], acc[0][1], 0, 0, 0); \
      acc[1][1] = __builtin_amdgcn_mfma_i32_32x32x32_i8(aq1, SET[1 * 2 + j_], acc[1][1], 0, 0, 0); \
    }                                                                         \
  } while (0)

// one K-tile, one barrier.  bX holds kw01(T) on entry; exits with bX=kw01(T+1).
#define KTILE(T, BUF) do {                                                    \
    const int tp1_ = ((T) + 1) & 31;                                          \
    const int tp2_ = ((T) + 2) & 31;                                          \
    LDBH(bY, (T), 2);                                                         \
    FENCE();                                                                  \
    PRIO1(); MFH(BUF, bX, 0); PRIO0();                                        \
    LDBH(bX, tp1_, 0);                                                        \
    FENCE();                                                                  \
    PRIO1(); MFH(BUF, bY, 2); PRIO0();                                        \
    FENCE();                                                                  \
    VM4(); BAR(); FENCE();                                                    \
    STGA(BUF, tp2_);                                                          \
  } while (0)

__global__ __launch_bounds__(256, 4) void qgemm_i8_slim(const char* __restrict__ Ai,
                                                        const char* __restrict__ Bi,
                                                        const float* __restrict__ scales,
                                                        float* __restrict__ out) {
  __shared__ __align__(16) char AsB[2 * 16384];  // 2-deep A K-tiles (128 rows x 128 k)

  const int tid  = threadIdx.x;
  const int lane = tid & 63;
  const int wave = tid >> 6;
  const int wr = wave >> 1;  // 0..1 -> 64 output rows
  const int wc = wave & 1;   // 0..1 -> 64 output cols

  const int bid = blockIdx.x;                  // 0..2047
  const int sbi = bid >> 4, li = bid & 15;
  const int mb = (sbi & 15) * 4 + (li & 3);    // 0..63
  const int nb = (sbi >> 4) * 4 + (li >> 2);   // 0..31
  const int m0 = mb * 128, n0 = nb * 128;

  // A staging sources (r16/r17-verified map): dest unit (r*256+tid) ->
  // mblk_local r, kw=(tid>>6)&3, lane=tid&63; mblk section 131072B, K-tile 4096B
  const char* pA4[4];
#pragma unroll
  for (int r = 0; r < 4; ++r) {
    pA4[r] = Ai + (size_t)(mb * 4 + r) * 131072 +
             (size_t)(((tid >> 6) & 3) * 64 + (tid & 63)) * 16;
  }

  // B base: fragment-linear, this wave's nblk pair
  const char* pB0 = Bi + (size_t)(nb * 4 + wc * 2) * 131072 + lane * 16;

  const int l16 = lane * 16;
  const int abase = wr * 8192;  // wave's 2 mblk slabs (fm via +4096)

  i32x16 acc[2][2];
#pragma unroll
  for (int i = 0; i < 2; ++i)
#pragma unroll
    for (int j = 0; j < 2; ++j)
      acc[i][j] = (i32x16)(0);

  int4v bX[4], bY[4];  // kw01 / kw23 half-chunks (static indexing)

  // ---- prologue: stage tiles 0,1; bX = kw01(0); vmcnt(4) forces both stages ----
  STGA(0, 0);
  STGA(1, 1);
  LDBH(bX, 0, 0);
  asm volatile("s_waitcnt vmcnt(4)" ::: "memory");
  BAR(); FENCE();

  // ---- main loop: 16 iters x 2 K-tiles; buf = T&1 ----
  for (int it = 0; it < 16; ++it) {
    const int tb = it * 2;
    KTILE(tb + 0, 0);
    KTILE(tb + 1, 1);
  }

  asm volatile("s_waitcnt vmcnt(0)" ::: "memory");  // drain trailing dead stages

  // ---- epilogue: C/D col=lane&31, row=(reg&3)+8*(reg>>2)+4*(lane>>5);
  //      out = (s[n]/QS) * acc   (zp folded exactly into Bi) ----
  const int hi = lane >> 5;
#pragma unroll
  for (int fm = 0; fm < 2; ++fm) {
    const int gr0 = m0 + wr * 64 + fm * 32 + hi * 4;
#pragma unroll
    for (int fn = 0; fn < 2; ++fn) {
      const i32x16 c = acc[fm][fn];
      const int gc = n0 + wc * 64 + fn * 32 + (lane & 31);
      const float sn = scales[gc] * INVQS;
#pragma unroll
      for (int rg = 0; rg < 16; ++rg) {
        const int gr = gr0 + (rg & 3) + 8 * (rg >> 2);
        out[(size_t)gr * NDIM + gc] = sn * (float)c[rg];
      }
    }
  }
}

// ---------------- fallback: fused f32-input kernel (r3, proven) ----------------
#define BM 128
#define BN 128
#define BK 64
#define NKT (KDIM / BK)
#define LDA 72
__global__ __launch_bounds__(256) void qgemm_fused_f32(
    const float* __restrict__ x, const int* __restrict__ qweight,
    const int* __restrict__ qzeros, const float* __restrict__ scales,
    float* __restrict__ out) {
  __shared__ __align__(16) short As[BM * LDA];
  __shared__ __align__(16) short Bs[BN * LDA];

  const int tid = threadIdx.x;
  const int lane = tid & 63;
  const int wave = tid >> 6;
  const int wr = wave >> 1, wc = wave & 1;
  const int bid = blockIdx.x;
  const int sbq = bid >> 4, li = bid & 15;
  const int mb = (sbq & 15) * 4 + (li & 3);
  const int nb = (sbq >> 4) * 4 + (li >> 2);
  const int m0 = mb * BM, n0 = nb * BN;

  const int ncol = tid & 127;
  const int kp_base = (tid >> 7) * 4;
  const int n_g = n0 + ncol;
  const float s = scales[n_g];
  const int zw = qzeros[n_g >> 3];
  const int zp1 = ((zw >> ((n_g & 7) * 4)) & 0xF) + 1;
  const float sz = -(float)zp1 * s;

  const int arow0 = tid >> 3;
  const int acol = (tid & 7) * 8;
  const int* qwp = qweight + (size_t)kp_base * NDIM + n_g;

  f32x4 af[8];
  {
    const float* xfp = x + (size_t)(m0 + arow0) * KDIM + acol;
#pragma unroll
    for (int g = 0; g < 4; ++g) {
      af[2 * g]     = *(const f32x4*)(xfp + (size_t)g * 32 * KDIM);
      af[2 * g + 1] = *(const f32x4*)(xfp + (size_t)g * 32 * KDIM + 4);
    }
  }
  int qw0 = qwp[0], qw1 = qwp[NDIM], qw2 = qwp[2 * NDIM], qw3 = qwp[3 * NDIM];

  f32x4 acc[4][4];
#pragma unroll
  for (int i = 0; i < 4; ++i)
#pragma unroll
    for (int j = 0; j < 4; ++j)
      acc[i][j] = (f32x4)(0.f);

  const int lr = lane & 15, kh = lane >> 4;

  for (int kt = 0; kt < NKT; ++kt) {
    __syncthreads();
#pragma unroll
    for (int g = 0; g < 4; ++g) {
      short8 v;
#pragma unroll
      for (int j = 0; j < 4; ++j) {
        v[j]     = (short)f2bf(af[2 * g][j]);
        v[4 + j] = (short)f2bf(af[2 * g + 1][j]);
      }
      *(short8*)&As[(arow0 + g * 32) * LDA + acol] = v;
    }
    {
      const int qq[4] = {qw0, qw1, qw2, qw3};
#pragma unroll
      for (int r = 0; r < 4; ++r) {
        const int w = qq[r];
        short8 v;
#pragma unroll
        for (int j = 0; j < 8; ++j)
          v[j] = (short)f2bf(fmaf((float)((w >> (4 * j)) & 0xF), s, sz));
        *(short8*)&Bs[ncol * LDA + (kp_base + r) * 8] = v;
      }
    }
    if (kt + 1 < NKT) {
      const float* xp = x + (size_t)(m0 + arow0) * KDIM + (size_t)(kt + 1) * BK + acol;
#pragma unroll
      for (int g = 0; g < 4; ++g) {
        af[2 * g]     = *(const f32x4*)(xp + (size_t)g * 32 * KDIM);
        af[2 * g + 1] = *(const f32x4*)(xp + (size_t)g * 32 * KDIM + 4);
      }
      const int* p = qwp + (size_t)(kt + 1) * 8 * NDIM;
      qw0 = p[0]; qw1 = p[NDIM]; qw2 = p[2 * NDIM]; qw3 = p[3 * NDIM];
    }
    __syncthreads();
#pragma unroll
    for (int ks = 0; ks < 2; ++ks) {
      const int kb = (ks * 4 + kh) * 8;
      short8 a[4], bb[4];
#pragma unroll
      for (int mf = 0; mf < 4; ++mf)
        a[mf] = *(const short8*)&As[(wr * 64 + mf * 16 + lr) * LDA + kb];
#pragma unroll
      for (int nf = 0; nf < 4; ++nf)
        bb[nf] = *(const short8*)&Bs[(wc * 64 + nf * 16 + lr) * LDA + kb];
#pragma unroll
      for (int mf = 0; mf < 4; ++mf)
#pragma unroll
        for (int nf = 0; nf < 4; ++nf)
          acc[mf][nf] = __builtin_amdgcn_mfma_f32_16x16x32_bf16(a[mf], bb[nf], acc[mf][nf], 0, 0, 0);
    }
  }
#pragma unroll
  for (int mf = 0; mf < 4; ++mf)
#pragma unroll
    for (int nf = 0; nf < 4; ++nf) {
      const f32x4 c = acc[mf][nf];
      const int gc = n0 + wc * 64 + nf * 16 + lr;
#pragma unroll
      for (int rg = 0; rg < 4; ++rg)
        out[(size_t)(m0 + wr * 64 + mf * 16 + kh * 4 + rg) * NDIM + gc] = c[rg];
    }
}

extern "C" void kernel_launch(void* const* d_in, const int* in_sizes, int n_in,
                              void* d_out, int out_size, void* d_ws, size_t ws_size,
                              hipStream_t stream) {
  const float* x      = (const float*)d_in[0];  // fp16 ref stored as f32 on device
  const int* qweight  = (const int*)d_in[2];    // [K/8][N] int32
  const int* qzeros   = (const int*)d_in[3];    // [1][N/8] int32
  const float* scales = (const float*)d_in[4];  // fp16 ref stored as f32
  float* out = (float*)d_out;

  const size_t xi_bytes = (size_t)MDIM * KDIM;      // 32 MB
  const size_t wi_bytes = (size_t)NDIM * KDIM;      // 16 MB

  if (ws_size >= xi_bytes + wi_bytes) {
    char* xi = (char*)d_ws;
    char* wi = (char*)d_ws + xi_bytes;
    prep_kernel<<<8192 + 4096, 256, 0, stream>>>(x, xi, qweight, qzeros, wi);
    const int grid = (MDIM / 128) * (NDIM / 128);  // 2048
    qgemm_i8_slim<<<grid, 256, 0, stream>>>(xi, wi, scales, out);
  } else {
    const int grid = (MDIM / BM) * (NDIM / BN);  // 2048
    qgemm_fused_f32<<<grid, 256, 0, stream>>>(x, qweight, qzeros, scales, out);
  }
}

// Round 21
// 171.916 us; speedup vs baseline: 1.1663x; 1.1663x over previous
//
#include <hip/hip_runtime.h>

#define MDIM 8192
#define NDIM 4096
#define KDIM 4096
#define QS 21.1666666f      // 127/6
#define INVQS (6.0f / 127.0f)

typedef __attribute__((ext_vector_type(8))) short short8;
typedef __attribute__((ext_vector_type(4))) float f32x4;
typedef __attribute__((ext_vector_type(4))) int int4v;
typedef __attribute__((ext_vector_type(16))) int i32x16;
typedef __attribute__((ext_vector_type(16))) char char16;
typedef unsigned short u16;
typedef unsigned int u32;

__device__ __forceinline__ u16 f2bf(float f) {
  return __builtin_bit_cast(u16, static_cast<__bf16>(f));
}

// ---------------- prepass: x f32 -> i8 frag-linear; W -> (q-zp1) i8 frag-linear ----
// (r16-verified; numerics frozen)
__global__ __launch_bounds__(256) void prep_kernel(const float* __restrict__ x,
                                                   char* __restrict__ xi,
                                                   const int* __restrict__ qw,
                                                   const int* __restrict__ qz,
                                                   char* __restrict__ wi) {
  const int b = blockIdx.x;
  if (b < 8192) {
    const u32 u = b * 256 + threadIdx.x;      // 0..2097151
    const int lane = u & 63;
    const int kblk = (u >> 6) & 127;
    const int mblk = u >> 13;                 // 0..255
    const int m = mblk * 32 + (lane & 31);
    const int k0 = kblk * 32 + (lane >> 5) * 16;
    const float* p = x + (size_t)m * KDIM + k0;
    char16 v;
#pragma unroll
    for (int c4 = 0; c4 < 4; ++c4) {
      const f32x4 a = *(const f32x4*)(p + c4 * 4);
#pragma unroll
      for (int j = 0; j < 4; ++j) {
        const int q = __float2int_rn(fminf(fmaxf(a[j] * QS, -127.f), 127.f));
        v[c4 * 4 + j] = (char)q;
      }
    }
    *(char16*)(xi + (size_t)u * 16) = v;
  } else {
    const u32 u = (b - 8192) * 256 + threadIdx.x;  // 0..1048575
    const int lane = u & 63;
    const int kblk = (u >> 6) & 127;
    const int nblk = u >> 13;                 // 0..127
    const int n = nblk * 32 + (lane & 31);
    const int kp0 = kblk * 4 + (lane >> 5) * 2;
    const int zw = qz[n >> 3];
    const int zp1 = ((zw >> ((n & 7) * 4)) & 0xF) + 1;
    char16 v;
#pragma unroll
    for (int h = 0; h < 2; ++h) {
      const int w = qw[(size_t)(kp0 + h) * NDIM + n];
#pragma unroll
      for (int j = 0; j < 8; ++j)
        v[h * 8 + j] = (char)(((w >> (4 * j)) & 0xF) - zp1);
    }
    *(char16*)(wi + (size_t)u * 16) = v;
  }
}

// ---------------- main GEMM: i8 32x32x32, 128x256 tile, 2 blocks/CU (r17 schedule) --
// + XCD-aware block swizzle (bijective 8x128): each XCD's L2 keeps one B stripe.
#define BAR()    __builtin_amdgcn_s_barrier()
#define FENCE()  __builtin_amdgcn_sched_barrier(0)
#define VM8()    asm volatile("s_waitcnt vmcnt(8)" ::: "memory")
#define PRIO1()  __builtin_amdgcn_s_setprio(1)
#define PRIO0()  __builtin_amdgcn_s_setprio(0)

// stage A K-tile T (128 rows x 128 k i8 = 16KB) into buffer BUF: 4 glds rounds
#define STGA(BUF, T) do {                                                     \
    _Pragma("unroll")                                                         \
    for (int r_ = 0; r_ < 4; ++r_) {                                          \
      __builtin_amdgcn_global_load_lds(                                       \
        (const __attribute__((address_space(1))) void*)                       \
          (pA4[r_] + (size_t)(T) * 4096),                                     \
        (__attribute__((address_space(3))) void*)                             \
          (AsB + (BUF) * 16384 + r_ * 4096 + tid * 16), 16, 0, 0);            \
    }                                                                         \
  } while (0)

// load K-tile TN's 8 B-fragments (fn 0..1 x kw 0..3, 1KB each) into DST
#define LDB(DST, TN) do {                                                     \
    _Pragma("unroll")                                                         \
    for (int fn_ = 0; fn_ < 2; ++fn_)                                         \
      _Pragma("unroll")                                                       \
      for (int kw_ = 0; kw_ < 4; ++kw_)                                       \
        DST[fn_ * 4 + kw_] = *(const int4v*)(pB0 + (size_t)fn_ * 131072 +     \
            (size_t)(TN) * 4096 + kw_ * 1024);                                \
  } while (0)

// MFMA one K-tile (128 k) from A-LDS buffer BUF with B register set BSET
#define MTILE(BUF, BSET) do {                                                 \
    _Pragma("unroll")                                                         \
    for (int kw_ = 0; kw_ < 4; ++kw_) {                                       \
      const char* b_ = AsB + (BUF) * 16384 + arb + kw_ * 1024;                \
      int4v aq0 = *(const int4v*)(b_);                                        \
      int4v aq1 = *(const int4v*)(b_ + 4096);                                 \
      int4v aq2 = *(const int4v*)(b_ + 8192);                                 \
      int4v aq3 = *(const int4v*)(b_ + 12288);                                \
      acc[0][0] = __builtin_amdgcn_mfma_i32_32x32x32_i8(aq0, BSET[0 * 4 + kw_], acc[0][0], 0, 0, 0); \
      acc[1][0] = __builtin_amdgcn_mfma_i32_32x32x32_i8(aq1, BSET[0 * 4 + kw_], acc[1][0], 0, 0, 0); \
      acc[2][0] = __builtin_amdgcn_mfma_i32_32x32x32_i8(aq2, BSET[0 * 4 + kw_], acc[2][0], 0, 0, 0); \
      acc[3][0] = __builtin_amdgcn_mfma_i32_32x32x32_i8(aq3, BSET[0 * 4 + kw_], acc[3][0], 0, 0, 0); \
      acc[0][1] = __builtin_amdgcn_mfma_i32_32x32x32_i8(aq0, BSET[1 * 4 + kw_], acc[0][1], 0, 0, 0); \
      acc[1][1] = __builtin_amdgcn_mfma_i32_32x32x32_i8(aq1, BSET[1 * 4 + kw_], acc[1][1], 0, 0, 0); \
      acc[2][1] = __builtin_amdgcn_mfma_i32_32x32x32_i8(aq2, BSET[1 * 4 + kw_], acc[2][1], 0, 0, 0); \
      acc[3][1] = __builtin_amdgcn_mfma_i32_32x32x32_i8(aq3, BSET[1 * 4 + kw_], acc[3][1], 0, 0, 0); \
    }                                                                         \
  } while (0)

// 2 K-tiles per barrier (r14/r16/r17-verified ledger): vmcnt(8) forces both stages
#define PHASE2(T, C0, C1, S0, S1) do {                                        \
    const int tp1_ = (T) + 1;                                                 \
    const int tp2_ = ((T) + 2) & 31;                                          \
    const int tp3_ = ((T) + 3) & 31;                                          \
    LDB(bB, tp1_);                                                            \
    STGA(S0, tp2_);                                                           \
    STGA(S1, tp3_);                                                           \
    FENCE();                                                                  \
    PRIO1(); MTILE(C0, bA); PRIO0(); FENCE();                                 \
    LDB(bA, tp2_);                                                            \
    FENCE();                                                                  \
    PRIO1(); MTILE(C1, bB); PRIO0(); FENCE();                                 \
    VM8(); BAR(); FENCE();                                                    \
  } while (0)

__global__ __launch_bounds__(256, 2) void qgemm_i8_x(const char* __restrict__ Ai,
                                                     const char* __restrict__ Bi,
                                                     const float* __restrict__ scales,
                                                     float* __restrict__ out) {
  __shared__ __align__(16) char AsB[4 * 16384];  // 4-deep A K-tiles (128 rows x 128 k)

  const int tid  = threadIdx.x;
  const int lane = tid & 63;
  const int wcol = tid >> 6;   // 0..3 -> 64 output cols each (4 waves, 1 wave-row)

  // XCD-aware bijective swizzle (grid 1024 = 8 x 128): round-robin XCD x gets
  // contiguous swizzled range [x*128, x*128+128) -> its B stripe is L2-resident.
  const int bid0 = blockIdx.x;
  const int bid = ((bid0 & 7) << 7) | (bid0 >> 3);

  const int sbi = bid >> 4, li = bid & 15;
  const int mb = (sbi & 15) * 4 + (li & 3);    // 0..63
  const int nb = (sbi >> 4) * 4 + (li >> 2);   // 0..15
  const int m0 = mb * 128, n0 = nb * 256;

  // A staging sources (r16/r17-verified map): dest unit (r*256+tid) ->
  // mblk_local r, kw=(tid>>6)&3, lane=tid&63; mblk section 131072B, K-tile 4096B
  const char* pA4[4];
#pragma unroll
  for (int r = 0; r < 4; ++r) {
    pA4[r] = Ai + (size_t)(mb * 4 + r) * 131072 +
             (size_t)(((tid >> 6) & 3) * 64 + (tid & 63)) * 16;
  }

  // B base: fragment-linear, this wave's nblk pair
  const char* pB0 = Bi + (size_t)(nb * 8 + wcol * 2) * 131072 + lane * 16;

  // A fragment read base: byte = fm*4096 + kw*1024 + lane*16 (contiguous b128)
  const int arb = lane * 16;

  i32x16 acc[4][2];
#pragma unroll
  for (int i = 0; i < 4; ++i)
#pragma unroll
    for (int j = 0; j < 2; ++j)
      acc[i][j] = (i32x16)(0);

  int4v bA[8], bB[8];

  // ---- prologue: stage tiles 0,1; B(0) in flight; vmcnt(8) forces stages ----
  STGA(0, 0);
  STGA(1, 1);
  LDB(bA, 0);
  asm volatile("s_waitcnt vmcnt(8)" ::: "memory");
  BAR(); FENCE();

  // ---- main loop: 8 iters x 4 K-tiles (2 barriers per iter); 32 tiles total ----
  for (int it = 0; it < 8; ++it) {
    const int tb = it * 4;
    PHASE2(tb + 0, 0, 1, 2, 3);
    PHASE2(tb + 2, 2, 3, 0, 1);
  }

  asm volatile("s_waitcnt vmcnt(0)" ::: "memory");  // drain wrapped dead stages

  // ---- epilogue: C/D col=lane&31, row=(reg&3)+8*(reg>>2)+4*(lane>>5);
  //      out = (s[n]/QS) * acc   (zp folded exactly into Bi) ----
  const int hi = lane >> 5;
#pragma unroll
  for (int fm = 0; fm < 4; ++fm) {
    const int gr0 = m0 + fm * 32 + hi * 4;
#pragma unroll
    for (int fn = 0; fn < 2; ++fn) {
      const i32x16 c = acc[fm][fn];
      const int gc = n0 + wcol * 64 + fn * 32 + (lane & 31);
      const float sn = scales[gc] * INVQS;
#pragma unroll
      for (int rg = 0; rg < 16; ++rg) {
        const int gr = gr0 + (rg & 3) + 8 * (rg >> 2);
        out[(size_t)gr * NDIM + gc] = sn * (float)c[rg];
      }
    }
  }
}

// ---------------- fallback: fused f32-input kernel (r3, proven) ----------------
#define BM 128
#define BN 128
#define BK 64
#define NKT (KDIM / BK)
#define LDA 72
__global__ __launch_bounds__(256) void qgemm_fused_f32(
    const float* __restrict__ x, const int* __restrict__ qweight,
    const int* __restrict__ qzeros, const float* __restrict__ scales,
    float* __restrict__ out) {
  __shared__ __align__(16) short As[BM * LDA];
  __shared__ __align__(16) short Bs[BN * LDA];

  const int tid = threadIdx.x;
  const int lane = tid & 63;
  const int wave = tid >> 6;
  const int wr = wave >> 1, wc = wave & 1;
  const int bid = blockIdx.x;
  const int sbq = bid >> 4, li = bid & 15;
  const int mb = (sbq & 15) * 4 + (li & 3);
  const int nb = (sbq >> 4) * 4 + (li >> 2);
  const int m0 = mb * BM, n0 = nb * BN;

  const int ncol = tid & 127;
  const int kp_base = (tid >> 7) * 4;
  const int n_g = n0 + ncol;
  const float s = scales[n_g];
  const int zw = qzeros[n_g >> 3];
  const int zp1 = ((zw >> ((n_g & 7) * 4)) & 0xF) + 1;
  const float sz = -(float)zp1 * s;

  const int arow0 = tid >> 3;
  const int acol = (tid & 7) * 8;
  const int* qwp = qweight + (size_t)kp_base * NDIM + n_g;

  f32x4 af[8];
  {
    const float* xfp = x + (size_t)(m0 + arow0) * KDIM + acol;
#pragma unroll
    for (int g = 0; g < 4; ++g) {
      af[2 * g]     = *(const f32x4*)(xfp + (size_t)g * 32 * KDIM);
      af[2 * g + 1] = *(const f32x4*)(xfp + (size_t)g * 32 * KDIM + 4);
    }
  }
  int qw0 = qwp[0], qw1 = qwp[NDIM], qw2 = qwp[2 * NDIM], qw3 = qwp[3 * NDIM];

  f32x4 acc[4][4];
#pragma unroll
  for (int i = 0; i < 4; ++i)
#pragma unroll
    for (int j = 0; j < 4; ++j)
      acc[i][j] = (f32x4)(0.f);

  const int lr = lane & 15, kh = lane >> 4;

  for (int kt = 0; kt < NKT; ++kt) {
    __syncthreads();
#pragma unroll
    for (int g = 0; g < 4; ++g) {
      short8 v;
#pragma unroll
      for (int j = 0; j < 4; ++j) {
        v[j]     = (short)f2bf(af[2 * g][j]);
        v[4 + j] = (short)f2bf(af[2 * g + 1][j]);
      }
      *(short8*)&As[(arow0 + g * 32) * LDA + acol] = v;
    }
    {
      const int qq[4] = {qw0, qw1, qw2, qw3};
#pragma unroll
      for (int r = 0; r < 4; ++r) {
        const int w = qq[r];
        short8 v;
#pragma unroll
        for (int j = 0; j < 8; ++j)
          v[j] = (short)f2bf(fmaf((float)((w >> (4 * j)) & 0xF), s, sz));
        *(short8*)&Bs[ncol * LDA + (kp_base + r) * 8] = v;
      }
    }
    if (kt + 1 < NKT) {
      const float* xp = x + (size_t)(m0 + arow0) * KDIM + (size_t)(kt + 1) * BK + acol;
#pragma unroll
      for (int g = 0; g < 4; ++g) {
        af[2 * g]     = *(const f32x4*)(xp + (size_t)g * 32 * KDIM);
        af[2 * g + 1] = *(const f32x4*)(xp + (size_t)g * 32 * KDIM + 4);
      }
      const int* p = qwp + (size_t)(kt + 1) * 8 * NDIM;
      qw0 = p[0]; qw1 = p[NDIM]; qw2 = p[2 * NDIM]; qw3 = p[3 * NDIM];
    }
    __syncthreads();
#pragma unroll
    for (int ks = 0; ks < 2; ++ks) {
      const int kb = (ks * 4 + kh) * 8;
      short8 a[4], bb[4];
#pragma unroll
      for (int mf = 0; mf < 4; ++mf)
        a[mf] = *(const short8*)&As[(wr * 64 + mf * 16 + lr) * LDA + kb];
#pragma unroll
      for (int nf = 0; nf < 4; ++nf)
        bb[nf] = *(const short8*)&Bs[(wc * 64 + nf * 16 + lr) * LDA + kb];
#pragma unroll
      for (int mf = 0; mf < 4; ++mf)
#pragma unroll
        for (int nf = 0; nf < 4; ++nf)
          acc[mf][nf] = __builtin_amdgcn_mfma_f32_16x16x32_bf16(a[mf], bb[nf], acc[mf][nf], 0, 0, 0);
    }
  }
#pragma unroll
  for (int mf = 0; mf < 4; ++mf)
#pragma unroll
    for (int nf = 0; nf < 4; ++nf) {
      const f32x4 c = acc[mf][nf];
      const int gc = n0 + wc * 64 + nf * 16 + lr;
#pragma unroll
      for (int rg = 0; rg < 4; ++rg)
        out[(size_t)(m0 + wr * 64 + mf * 16 + kh * 4 + rg) * NDIM + gc] = c[rg];
    }
}

extern "C" void kernel_launch(void* const* d_in, const int* in_sizes, int n_in,
                              void* d_out, int out_size, void* d_ws, size_t ws_size,
                              hipStream_t stream) {
  const float* x      = (const float*)d_in[0];  // fp16 ref stored as f32 on device
  const int* qweight  = (const int*)d_in[2];    // [K/8][N] int32
  const int* qzeros   = (const int*)d_in[3];    // [1][N/8] int32
  const float* scales = (const float*)d_in[4];  // fp16 ref stored as f32
  float* out = (float*)d_out;

  const size_t xi_bytes = (size_t)MDIM * KDIM;      // 32 MB
  const size_t wi_bytes = (size_t)NDIM * KDIM;      // 16 MB

  if (ws_size >= xi_bytes + wi_bytes) {
    char* xi = (char*)d_ws;
    char* wi = (char*)d_ws + xi_bytes;
    prep_kernel<<<8192 + 4096, 256, 0, stream>>>(x, xi, qweight, qzeros, wi);
    const int grid = (MDIM / 128) * (NDIM / 256);  // 1024
    qgemm_i8_x<<<grid, 256, 0, stream>>>(xi, wi, scales, out);
  } else {
    const int grid = (MDIM / BM) * (NDIM / BN);  // 2048
    qgemm_fused_f32<<<grid, 256, 0, stream>>>(x, qweight, qzeros, scales, out);
  }
}